// Round 1
// baseline (1073.477 us; speedup 1.0000x reference)
//
#include <hip/hip_runtime.h>

#define WAVE 64

// ---------------- utility kernels ----------------

__global__ void k_zero(int* __restrict__ p, int n) {
    int i = blockIdx.x * 256 + threadIdx.x;
    if (i < n) p[i] = 0;
}

__global__ void k_count(const int* __restrict__ dst, int E, int N, int* __restrict__ deg) {
    int i = blockIdx.x * 256 + threadIdx.x;
    if (i < E + N) {
        int d = (i < E) ? dst[i] : (i - E);
        atomicAdd(&deg[d], 1);
    }
}

// inclusive scan per 256-block
__global__ void k_scan1(const int* __restrict__ deg, int* __restrict__ incl,
                        int* __restrict__ bsum, int N) {
    __shared__ int sh[256];
    int i = blockIdx.x * 256 + threadIdx.x;
    int v = (i < N) ? deg[i] : 0;
    sh[threadIdx.x] = v;
    __syncthreads();
    for (int o = 1; o < 256; o <<= 1) {
        int u = (threadIdx.x >= o) ? sh[threadIdx.x - o] : 0;
        __syncthreads();
        sh[threadIdx.x] += u;
        __syncthreads();
    }
    if (i < N) incl[i] = sh[threadIdx.x];
    if (threadIdx.x == 255) bsum[blockIdx.x] = sh[255];
}

// single-block exclusive scan of block sums (nb <= 512)
__global__ void k_scan2(int* __restrict__ bsum, int nb) {
    __shared__ int sh[512];
    int t = threadIdx.x;
    int v = (t < nb) ? bsum[t] : 0;
    sh[t] = v;
    __syncthreads();
    for (int o = 1; o < 512; o <<= 1) {
        int u = (t >= o) ? sh[t - o] : 0;
        __syncthreads();
        sh[t] += u;
        __syncthreads();
    }
    if (t < nb) bsum[t] = sh[t] - v;  // exclusive
}

__global__ void k_scan3(const int* __restrict__ incl, const int* __restrict__ deg,
                        const int* __restrict__ bsum, int* __restrict__ offs, int N, int Etot) {
    int i = blockIdx.x * 256 + threadIdx.x;
    if (i < N) offs[i] = incl[i] - deg[i] + bsum[i >> 8];
    if (i == 0) offs[N] = Etot;
}

__global__ void k_scatter(const int* __restrict__ src, const int* __restrict__ dst, int E, int N,
                          const int* __restrict__ offs, int* __restrict__ cursor,
                          int* __restrict__ csr_src) {
    int i = blockIdx.x * 256 + threadIdx.x;
    if (i >= E + N) return;
    int d, s;
    if (i < E) { d = dst[i]; s = src[i]; }
    else       { d = i - E; s = i - E; }
    int pos = offs[d] + atomicAdd(&cursor[d], 1);
    csr_src[pos] = s;
}

// ---------------- GEMM: C[M x 128] = A[M x 128] @ W[128 x 128] ----------------
// 64x64 tile, 4x4 microtile, K-tiles of 32; A staged transposed in LDS.

#define TM 64
#define TN 64
#define TK 32

__global__ __launch_bounds__(256) void k_gemm128(const float* __restrict__ A,
                                                 const float* __restrict__ W,
                                                 float* __restrict__ C, int M) {
    __shared__ float As[TK][TM];  // As[k][m]
    __shared__ float Bs[TK][TN];  // Bs[k][n]
    int tid = threadIdx.x;
    int tx = tid & 15, ty = tid >> 4;
    int rowBase = blockIdx.y * TM;
    int col0 = blockIdx.x * TN;

    float acc[4][4] = {{0.f}};

    int arow = tid >> 2, akq = (tid & 3) * 8;   // A staging: 64 rows x 32 k, 8 floats/thread
    int brow = tid >> 3, bnq = (tid & 7) * 8;   // W staging: 32 k x 64 n, 8 floats/thread

    for (int k0 = 0; k0 < 128; k0 += TK) {
        int grow = rowBase + arow;
        float4 a0 = {0.f, 0.f, 0.f, 0.f}, a1 = {0.f, 0.f, 0.f, 0.f};
        if (grow < M) {
            const float* ap = A + (size_t)grow * 128 + k0 + akq;
            a0 = *(const float4*)ap;
            a1 = *(const float4*)(ap + 4);
        }
        const float* wp = W + (size_t)(k0 + brow) * 128 + col0 + bnq;
        float4 b0 = *(const float4*)wp;
        float4 b1 = *(const float4*)(wp + 4);

        __syncthreads();  // previous iteration's reads done before overwrite
        As[akq + 0][arow] = a0.x; As[akq + 1][arow] = a0.y;
        As[akq + 2][arow] = a0.z; As[akq + 3][arow] = a0.w;
        As[akq + 4][arow] = a1.x; As[akq + 5][arow] = a1.y;
        As[akq + 6][arow] = a1.z; As[akq + 7][arow] = a1.w;
        *(float4*)&Bs[brow][bnq]     = b0;
        *(float4*)&Bs[brow][bnq + 4] = b1;
        __syncthreads();

#pragma unroll
        for (int kk = 0; kk < TK; ++kk) {
            float4 av = *(const float4*)&As[kk][ty * 4];
            float4 bv = *(const float4*)&Bs[kk][tx * 4];
            acc[0][0] += av.x * bv.x; acc[0][1] += av.x * bv.y;
            acc[0][2] += av.x * bv.z; acc[0][3] += av.x * bv.w;
            acc[1][0] += av.y * bv.x; acc[1][1] += av.y * bv.y;
            acc[1][2] += av.y * bv.z; acc[1][3] += av.y * bv.w;
            acc[2][0] += av.z * bv.x; acc[2][1] += av.z * bv.y;
            acc[2][2] += av.z * bv.z; acc[2][3] += av.z * bv.w;
            acc[3][0] += av.w * bv.x; acc[3][1] += av.w * bv.y;
            acc[3][2] += av.w * bv.z; acc[3][3] += av.w * bv.w;
        }
    }

#pragma unroll
    for (int i = 0; i < 4; ++i) {
        int row = rowBase + ty * 4 + i;
        if (row < M) {
            float4 o = {acc[i][0], acc[i][1], acc[i][2], acc[i][3]};
            *(float4*)&C[(size_t)row * 128 + col0 + tx * 4] = o;
        }
    }
}

// ---------------- per-row attention dots: es = h . a_src, ed = h . a_dst ----------------

__global__ __launch_bounds__(256) void k_esed(const float* __restrict__ h,
                                              const float* __restrict__ a_s,
                                              const float* __restrict__ a_d,
                                              float* __restrict__ es, float* __restrict__ ed,
                                              int N) {
    int w = (blockIdx.x * blockDim.x + threadIdx.x) >> 6;
    int lane = threadIdx.x & 63;
    if (w >= N) return;
    float2 v   = ((const float2*)(h + (size_t)w * 128))[lane];
    float2 as2 = ((const float2*)a_s)[lane];
    float2 ad2 = ((const float2*)a_d)[lane];
    float s = v.x * as2.x + v.y * as2.y;
    float d = v.x * ad2.x + v.y * ad2.y;
#pragma unroll
    for (int o = 32; o; o >>= 1) {
        s += __shfl_xor(s, o);
        d += __shfl_xor(d, o);
    }
    if (lane == 0) { es[w] = s; ed[w] = d; }
}

// ---------------- per-node softmax + aggregation (wave per node) ----------------

__global__ __launch_bounds__(256) void k_aggregate(const float* __restrict__ h,
                                                   const float* __restrict__ es,
                                                   const float* __restrict__ ed,
                                                   const int* __restrict__ csr_src,
                                                   const int* __restrict__ offs,
                                                   const float* __restrict__ bias,
                                                   float* __restrict__ out, int N) {
    int w = (blockIdx.x * blockDim.x + threadIdx.x) >> 6;
    int lane = threadIdx.x & 63;
    if (w >= N) return;
    int beg = offs[w], end = offs[w + 1];
    float edi = ed[w];

    // online softmax stats, lane-per-edge
    float m = -3.0e38f, s = 0.f;
    for (int j = beg + lane; j < end; j += WAVE) {
        int sj = csr_src[j];
        float e = es[sj] + edi;
        e = (e > 0.f) ? e : 0.2f * e;
        float mn = fmaxf(m, e);
        s = s * __expf(m - mn) + __expf(e - mn);
        m = mn;
    }
#pragma unroll
    for (int o = 32; o; o >>= 1) {
        float mo = __shfl_xor(m, o);
        float so = __shfl_xor(s, o);
        float mn = fmaxf(m, mo);
        s = s * __expf(m - mn) + so * __expf(mo - mn);
        m = mn;
    }
    float rinv = 1.f / s;

    float acc0 = 0.f, acc1 = 0.f;
    for (int j = beg; j < end; ++j) {
        int sj = csr_src[j];  // uniform across wave -> broadcast
        float e = es[sj] + edi;
        e = (e > 0.f) ? e : 0.2f * e;
        float wgt = __expf(e - m) * rinv;
        float2 v = ((const float2*)(h + (size_t)sj * 128))[lane];
        acc0 += wgt * v.x;
        acc1 += wgt * v.y;
    }
    float2 bv = ((const float2*)bias)[lane];
    float o0 = fmaxf(acc0 + bv.x, 0.f);
    float o1 = fmaxf(acc1 + bv.y, 0.f);
    ((float2*)(out + (size_t)w * 128))[lane] = make_float2(o0, o1);
}

// ---------------- mean-pool per graph + concat + final linear ----------------

__global__ __launch_bounds__(128) void k_pool(const float* __restrict__ h,
                                              const int* __restrict__ batch,
                                              const float* __restrict__ gf,
                                              const float* __restrict__ linW,
                                              const float* __restrict__ linb,
                                              float* __restrict__ out, int N) {
    int g = blockIdx.x, t = threadIdx.x;
    int lo, hi;
    { int a = 0, b = N; while (a < b) { int mid = (a + b) >> 1; if (batch[mid] < g) a = mid + 1; else b = mid; } lo = a; }
    { int a = lo, b = N; while (a < b) { int mid = (a + b) >> 1; if (batch[mid] < g + 1) a = mid + 1; else b = mid; } hi = a; }

    float sum = 0.f;
    for (int i = lo; i < hi; ++i) sum += h[(size_t)i * 128 + t];
    float pooled = sum / fmaxf((float)(hi - lo), 1.f);

    __shared__ float feat[144];
    feat[t] = pooled;
    if (t < 16) feat[128 + t] = gf[g * 16 + t];
    __syncthreads();
    if (t < 10) {
        float acc = linb[t];
        for (int k = 0; k < 144; ++k) acc += feat[k] * linW[k * 10 + t];
        out[g * 10 + t] = acc;
    }
}

// ---------------- launch ----------------

extern "C" void kernel_launch(void* const* d_in, const int* in_sizes, int n_in,
                              void* d_out, int out_size, void* d_ws, size_t ws_size,
                              hipStream_t stream) {
    const float* x    = (const float*)d_in[0];
    const int*   eidx = (const int*)d_in[1];
    const int*   batch = (const int*)d_in[2];
    const float* gf   = (const float*)d_in[3];
    const float* W1   = (const float*)d_in[4];
    const float* as1  = (const float*)d_in[5];
    const float* ad1  = (const float*)d_in[6];
    const float* b1   = (const float*)d_in[7];
    const float* W2   = (const float*)d_in[8];
    const float* as2  = (const float*)d_in[9];
    const float* ad2  = (const float*)d_in[10];
    const float* b2   = (const float*)d_in[11];
    const float* linW = (const float*)d_in[12];
    const float* linb = (const float*)d_in[13];
    float* out = (float*)d_out;

    const int N = in_sizes[0] / 128;
    const int E = in_sizes[1] / 2;
    const int Etot = E + N;
    const int* srcp = eidx;
    const int* dstp = eidx + E;

    char* ws = (char*)d_ws;
    size_t off = 0;
    auto alloc = [&](size_t bytes) -> void* {
        void* p = ws + off;
        off += (bytes + 255) & ~(size_t)255;
        return p;
    };
    float* hA     = (float*)alloc((size_t)N * 128 * 4);
    float* hB     = (float*)alloc((size_t)N * 128 * 4);
    float* es     = (float*)alloc((size_t)N * 4);
    float* ed     = (float*)alloc((size_t)N * 4);
    int*   deg    = (int*)alloc((size_t)N * 4);
    int*   cursor = (int*)alloc((size_t)N * 4);
    int*   offs   = (int*)alloc((size_t)(N + 1) * 4);
    int*   incl   = (int*)alloc((size_t)N * 4);
    int*   bsum   = (int*)alloc(512 * 4);
    int*   csr    = (int*)alloc((size_t)Etot * 4);

    // ---- build CSR by dst (same for both layers) ----
    k_zero<<<(N + 255) / 256, 256, 0, stream>>>(deg, N);
    k_zero<<<(N + 255) / 256, 256, 0, stream>>>(cursor, N);
    k_count<<<(Etot + 255) / 256, 256, 0, stream>>>(dstp, E, N, deg);
    int nb1 = (N + 255) / 256;
    k_scan1<<<nb1, 256, 0, stream>>>(deg, incl, bsum, N);
    k_scan2<<<1, 512, 0, stream>>>(bsum, nb1);
    k_scan3<<<nb1, 256, 0, stream>>>(incl, deg, bsum, offs, N, Etot);
    k_scatter<<<(Etot + 255) / 256, 256, 0, stream>>>(srcp, dstp, E, N, offs, cursor, csr);

    dim3 ggrid(128 / TN, (N + TM - 1) / TM);
    int wblocks = ((size_t)N * 64 + 255) / 256;

    // ---- layer 1 ----
    k_gemm128<<<ggrid, 256, 0, stream>>>(x, W1, hA, N);
    k_esed<<<wblocks, 256, 0, stream>>>(hA, as1, ad1, es, ed, N);
    k_aggregate<<<wblocks, 256, 0, stream>>>(hA, es, ed, csr, offs, b1, hB, N);

    // ---- layer 2 ----
    k_gemm128<<<ggrid, 256, 0, stream>>>(hB, W2, hA, N);
    k_esed<<<wblocks, 256, 0, stream>>>(hA, as2, ad2, es, ed, N);
    k_aggregate<<<wblocks, 256, 0, stream>>>(hA, es, ed, csr, offs, b2, hB, N);

    // ---- pool + head ----
    k_pool<<<64, 128, 0, stream>>>(hB, batch, gf, linW, linb, out, N);
}

// Round 2
// 761.180 us; speedup vs baseline: 1.4103x; 1.4103x over previous
//
#include <hip/hip_runtime.h>

#define WAVE 64

// ---------------- utility kernels ----------------

__global__ void k_zero(int* __restrict__ p, int n) {
    int i = blockIdx.x * 256 + threadIdx.x;
    if (i < n) p[i] = 0;
}

__global__ void k_count(const int* __restrict__ dst, int E, int N, int* __restrict__ deg) {
    int i = blockIdx.x * 256 + threadIdx.x;
    if (i < E + N) {
        int d = (i < E) ? dst[i] : (i - E);
        atomicAdd(&deg[d], 1);
    }
}

// inclusive scan per 256-block
__global__ void k_scan1(const int* __restrict__ deg, int* __restrict__ incl,
                        int* __restrict__ bsum, int N) {
    __shared__ int sh[256];
    int i = blockIdx.x * 256 + threadIdx.x;
    int v = (i < N) ? deg[i] : 0;
    sh[threadIdx.x] = v;
    __syncthreads();
    for (int o = 1; o < 256; o <<= 1) {
        int u = (threadIdx.x >= o) ? sh[threadIdx.x - o] : 0;
        __syncthreads();
        sh[threadIdx.x] += u;
        __syncthreads();
    }
    if (i < N) incl[i] = sh[threadIdx.x];
    if (threadIdx.x == 255) bsum[blockIdx.x] = sh[255];
}

// single-block exclusive scan of block sums (nb <= 512)
__global__ void k_scan2(int* __restrict__ bsum, int nb) {
    __shared__ int sh[512];
    int t = threadIdx.x;
    int v = (t < nb) ? bsum[t] : 0;
    sh[t] = v;
    __syncthreads();
    for (int o = 1; o < 512; o <<= 1) {
        int u = (t >= o) ? sh[t - o] : 0;
        __syncthreads();
        sh[t] += u;
        __syncthreads();
    }
    if (t < nb) bsum[t] = sh[t] - v;  // exclusive
}

__global__ void k_scan3(const int* __restrict__ incl, const int* __restrict__ deg,
                        const int* __restrict__ bsum, int* __restrict__ offs, int N, int Etot) {
    int i = blockIdx.x * 256 + threadIdx.x;
    if (i < N) offs[i] = incl[i] - deg[i] + bsum[i >> 8];
    if (i == 0) offs[N] = Etot;
}

__global__ void k_scatter(const int* __restrict__ src, const int* __restrict__ dst, int E, int N,
                          const int* __restrict__ offs, int* __restrict__ cursor,
                          int* __restrict__ csr_src) {
    int i = blockIdx.x * 256 + threadIdx.x;
    if (i >= E + N) return;
    int d, s;
    if (i < E) { d = dst[i]; s = src[i]; }
    else       { d = i - E; s = i - E; }
    int pos = offs[d] + atomicAdd(&cursor[d], 1);
    csr_src[pos] = s;
}

// ---------------- GEMM: C[M x 128] = A[M x 128] @ W[128 x 128] ----------------
// 64x64 tile, 4x4 microtile, K-tiles of 32; A staged transposed in LDS.

#define TM 64
#define TN 64
#define TK 32

__global__ __launch_bounds__(256) void k_gemm128(const float* __restrict__ A,
                                                 const float* __restrict__ W,
                                                 float* __restrict__ C, int M) {
    __shared__ float As[TK][TM];  // As[k][m]
    __shared__ float Bs[TK][TN];  // Bs[k][n]
    int tid = threadIdx.x;
    int tx = tid & 15, ty = tid >> 4;
    int rowBase = blockIdx.y * TM;
    int col0 = blockIdx.x * TN;

    float acc[4][4] = {{0.f}};

    int arow = tid >> 2, akq = (tid & 3) * 8;   // A staging: 64 rows x 32 k, 8 floats/thread
    int brow = tid >> 3, bnq = (tid & 7) * 8;   // W staging: 32 k x 64 n, 8 floats/thread

    for (int k0 = 0; k0 < 128; k0 += TK) {
        int grow = rowBase + arow;
        float4 a0 = {0.f, 0.f, 0.f, 0.f}, a1 = {0.f, 0.f, 0.f, 0.f};
        if (grow < M) {
            const float* ap = A + (size_t)grow * 128 + k0 + akq;
            a0 = *(const float4*)ap;
            a1 = *(const float4*)(ap + 4);
        }
        const float* wp = W + (size_t)(k0 + brow) * 128 + col0 + bnq;
        float4 b0 = *(const float4*)wp;
        float4 b1 = *(const float4*)(wp + 4);

        __syncthreads();  // previous iteration's reads done before overwrite
        As[akq + 0][arow] = a0.x; As[akq + 1][arow] = a0.y;
        As[akq + 2][arow] = a0.z; As[akq + 3][arow] = a0.w;
        As[akq + 4][arow] = a1.x; As[akq + 5][arow] = a1.y;
        As[akq + 6][arow] = a1.z; As[akq + 7][arow] = a1.w;
        *(float4*)&Bs[brow][bnq]     = b0;
        *(float4*)&Bs[brow][bnq + 4] = b1;
        __syncthreads();

#pragma unroll
        for (int kk = 0; kk < TK; ++kk) {
            float4 av = *(const float4*)&As[kk][ty * 4];
            float4 bv = *(const float4*)&Bs[kk][tx * 4];
            acc[0][0] += av.x * bv.x; acc[0][1] += av.x * bv.y;
            acc[0][2] += av.x * bv.z; acc[0][3] += av.x * bv.w;
            acc[1][0] += av.y * bv.x; acc[1][1] += av.y * bv.y;
            acc[1][2] += av.y * bv.z; acc[1][3] += av.y * bv.w;
            acc[2][0] += av.z * bv.x; acc[2][1] += av.z * bv.y;
            acc[2][2] += av.z * bv.z; acc[2][3] += av.z * bv.w;
            acc[3][0] += av.w * bv.x; acc[3][1] += av.w * bv.y;
            acc[3][2] += av.w * bv.z; acc[3][3] += av.w * bv.w;
        }
    }

#pragma unroll
    for (int i = 0; i < 4; ++i) {
        int row = rowBase + ty * 4 + i;
        if (row < M) {
            float4 o = {acc[i][0], acc[i][1], acc[i][2], acc[i][3]};
            *(float4*)&C[(size_t)row * 128 + col0 + tx * 4] = o;
        }
    }
}

// ---------------- per-row attention dots: es = h . a_src, ed = h . a_dst ----------------

__global__ __launch_bounds__(256) void k_esed(const float* __restrict__ h,
                                              const float* __restrict__ a_s,
                                              const float* __restrict__ a_d,
                                              float* __restrict__ es, float* __restrict__ ed,
                                              int N) {
    int w = (blockIdx.x * blockDim.x + threadIdx.x) >> 6;
    int lane = threadIdx.x & 63;
    if (w >= N) return;
    float2 v   = ((const float2*)(h + (size_t)w * 128))[lane];
    float2 as2 = ((const float2*)a_s)[lane];
    float2 ad2 = ((const float2*)a_d)[lane];
    float s = v.x * as2.x + v.y * as2.y;
    float d = v.x * ad2.x + v.y * ad2.y;
#pragma unroll
    for (int o = 32; o; o >>= 1) {
        s += __shfl_xor(s, o);
        d += __shfl_xor(d, o);
    }
    if (lane == 0) { es[w] = s; ed[w] = d; }
}

// ---------------- per-node softmax + aggregation (wave per node) ----------------

__global__ __launch_bounds__(256) void k_aggregate(const float* __restrict__ h,
                                                   const float* __restrict__ es,
                                                   const float* __restrict__ ed,
                                                   const int* __restrict__ csr_src,
                                                   const int* __restrict__ offs,
                                                   const float* __restrict__ bias,
                                                   float* __restrict__ out, int N) {
    int w = (blockIdx.x * blockDim.x + threadIdx.x) >> 6;
    int lane = threadIdx.x & 63;
    if (w >= N) return;
    int beg = offs[w], end = offs[w + 1];
    float edi = ed[w];

    // online softmax stats, lane-per-edge
    float m = -3.0e38f, s = 0.f;
    for (int j = beg + lane; j < end; j += WAVE) {
        int sj = csr_src[j];
        float e = es[sj] + edi;
        e = (e > 0.f) ? e : 0.2f * e;
        float mn = fmaxf(m, e);
        s = s * __expf(m - mn) + __expf(e - mn);
        m = mn;
    }
#pragma unroll
    for (int o = 32; o; o >>= 1) {
        float mo = __shfl_xor(m, o);
        float so = __shfl_xor(s, o);
        float mn = fmaxf(m, mo);
        s = s * __expf(m - mn) + so * __expf(mo - mn);
        m = mn;
    }
    float rinv = 1.f / s;

    float acc0 = 0.f, acc1 = 0.f;
    for (int j = beg; j < end; ++j) {
        int sj = csr_src[j];  // uniform across wave -> broadcast
        float e = es[sj] + edi;
        e = (e > 0.f) ? e : 0.2f * e;
        float wgt = __expf(e - m) * rinv;
        float2 v = ((const float2*)(h + (size_t)sj * 128))[lane];
        acc0 += wgt * v.x;
        acc1 += wgt * v.y;
    }
    float2 bv = ((const float2*)bias)[lane];
    float o0 = fmaxf(acc0 + bv.x, 0.f);
    float o1 = fmaxf(acc1 + bv.y, 0.f);
    ((float2*)(out + (size_t)w * 128))[lane] = make_float2(o0, o1);
}

// ---------------- pooling: parallel chunked sum with boundary-flush atomics ----------------

__global__ __launch_bounds__(128) void k_poolsum(const float* __restrict__ h,
                                                 const int* __restrict__ batch,
                                                 float* __restrict__ sums,   // [64][128]
                                                 int* __restrict__ cnt,      // [64]
                                                 int N) {
    int t = threadIdx.x;              // feature index
    int base = blockIdx.x * 256;      // 256-node chunk per block
    if (base >= N) return;
    int end = base + 256; if (end > N) end = N;

    int cur = batch[base];
    float acc = 0.f;
    int cnum = 0;
    for (int i = base; i < end; ++i) {
        int g = batch[i];
        if (g != cur) {
            atomicAdd(&sums[cur * 128 + t], acc);
            if (t == 0) atomicAdd(&cnt[cur], cnum);
            acc = 0.f; cnum = 0; cur = g;
        }
        acc += h[(size_t)i * 128 + t];
        ++cnum;
    }
    atomicAdd(&sums[cur * 128 + t], acc);
    if (t == 0) atomicAdd(&cnt[cur], cnum);
}

__global__ __launch_bounds__(64) void k_head(const float* __restrict__ sums,
                                             const int* __restrict__ cnt,
                                             const float* __restrict__ gf,
                                             const float* __restrict__ linW,
                                             const float* __restrict__ linb,
                                             float* __restrict__ out) {
    int g = blockIdx.x, t = threadIdx.x;
    __shared__ float feat[144];
    float c = fmaxf((float)cnt[g], 1.f);
    for (int k = t; k < 128; k += 64) feat[k] = sums[g * 128 + k] / c;
    if (t < 16) feat[128 + t] = gf[g * 16 + t];
    __syncthreads();
    if (t < 10) {
        float acc = linb[t];
        for (int k = 0; k < 144; ++k) acc += feat[k] * linW[k * 10 + t];
        out[g * 10 + t] = acc;
    }
}

// ---------------- launch ----------------

extern "C" void kernel_launch(void* const* d_in, const int* in_sizes, int n_in,
                              void* d_out, int out_size, void* d_ws, size_t ws_size,
                              hipStream_t stream) {
    const float* x    = (const float*)d_in[0];
    const int*   eidx = (const int*)d_in[1];
    const int*   batch = (const int*)d_in[2];
    const float* gf   = (const float*)d_in[3];
    const float* W1   = (const float*)d_in[4];
    const float* as1  = (const float*)d_in[5];
    const float* ad1  = (const float*)d_in[6];
    const float* b1   = (const float*)d_in[7];
    const float* W2   = (const float*)d_in[8];
    const float* as2  = (const float*)d_in[9];
    const float* ad2  = (const float*)d_in[10];
    const float* b2   = (const float*)d_in[11];
    const float* linW = (const float*)d_in[12];
    const float* linb = (const float*)d_in[13];
    float* out = (float*)d_out;

    const int N = in_sizes[0] / 128;
    const int E = in_sizes[1] / 2;
    const int Etot = E + N;
    const int* srcp = eidx;
    const int* dstp = eidx + E;

    char* ws = (char*)d_ws;
    size_t off = 0;
    auto alloc = [&](size_t bytes) -> void* {
        void* p = ws + off;
        off += (bytes + 255) & ~(size_t)255;
        return p;
    };
    float* hA     = (float*)alloc((size_t)N * 128 * 4);
    float* hB     = (float*)alloc((size_t)N * 128 * 4);
    float* es     = (float*)alloc((size_t)N * 4);
    float* ed     = (float*)alloc((size_t)N * 4);
    int*   deg    = (int*)alloc((size_t)N * 4);
    int*   cursor = (int*)alloc((size_t)N * 4);
    int*   offs   = (int*)alloc((size_t)(N + 1) * 4);
    int*   incl   = (int*)alloc((size_t)N * 4);
    int*   bsum   = (int*)alloc(512 * 4);
    float* psums  = (float*)alloc(64 * 128 * 4);
    int*   pcnt   = (int*)alloc(64 * 4);
    int*   csr    = (int*)alloc((size_t)Etot * 4);

    // ---- build CSR by dst (same for both layers) ----
    k_zero<<<(N + 255) / 256, 256, 0, stream>>>(deg, N);
    k_zero<<<(N + 255) / 256, 256, 0, stream>>>(cursor, N);
    // zero pooled sums (64*128 floats) + counts (64 ints): zero-bits == 0.0f
    k_zero<<<(64 * 128 + 64 + 255) / 256, 256, 0, stream>>>((int*)psums, 64 * 128 + 64);
    k_count<<<(Etot + 255) / 256, 256, 0, stream>>>(dstp, E, N, deg);
    int nb1 = (N + 255) / 256;
    k_scan1<<<nb1, 256, 0, stream>>>(deg, incl, bsum, N);
    k_scan2<<<1, 512, 0, stream>>>(bsum, nb1);
    k_scan3<<<nb1, 256, 0, stream>>>(incl, deg, bsum, offs, N, Etot);
    k_scatter<<<(Etot + 255) / 256, 256, 0, stream>>>(srcp, dstp, E, N, offs, cursor, csr);

    dim3 ggrid(128 / TN, (N + TM - 1) / TM);
    int wblocks = ((size_t)N * 64 + 255) / 256;

    // ---- layer 1 ----
    k_gemm128<<<ggrid, 256, 0, stream>>>(x, W1, hA, N);
    k_esed<<<wblocks, 256, 0, stream>>>(hA, as1, ad1, es, ed, N);
    k_aggregate<<<wblocks, 256, 0, stream>>>(hA, es, ed, csr, offs, b1, hB, N);

    // ---- layer 2 ----
    k_gemm128<<<ggrid, 256, 0, stream>>>(hB, W2, hA, N);
    k_esed<<<wblocks, 256, 0, stream>>>(hA, as2, ad2, es, ed, N);
    k_aggregate<<<wblocks, 256, 0, stream>>>(hA, es, ed, csr, offs, b2, hB, N);

    // ---- pool + head ----
    k_poolsum<<<(N + 255) / 256, 128, 0, stream>>>(hB, batch, psums, pcnt, N);
    k_head<<<64, 64, 0, stream>>>(psums, pcnt, gf, linW, linb, out);
}

// Round 3
// 753.055 us; speedup vs baseline: 1.4255x; 1.0108x over previous
//
#include <hip/hip_runtime.h>

#define WAVE 64

__device__ __forceinline__ ushort f2bf(float f) {
    union { float f; unsigned u; } v; v.f = f;
    unsigned r = v.u + 0x7FFF + ((v.u >> 16) & 1);
    return (ushort)(r >> 16);
}
__device__ __forceinline__ float bf2f(ushort u) {
    union { unsigned u; float f; } v; v.u = ((unsigned)u) << 16;
    return v.f;
}

// ---------------- utility kernels ----------------

__global__ void k_zero(int* __restrict__ p, int n) {
    int i = blockIdx.x * 256 + threadIdx.x;
    if (i < n) p[i] = 0;
}

__global__ void k_count(const int* __restrict__ dst, int E, int N, int* __restrict__ deg) {
    int i = blockIdx.x * 256 + threadIdx.x;
    if (i < E + N) {
        int d = (i < E) ? dst[i] : (i - E);
        atomicAdd(&deg[d], 1);
    }
}

// inclusive scan per 256-block
__global__ void k_scan1(const int* __restrict__ deg, int* __restrict__ incl,
                        int* __restrict__ bsum, int N) {
    __shared__ int sh[256];
    int i = blockIdx.x * 256 + threadIdx.x;
    int v = (i < N) ? deg[i] : 0;
    sh[threadIdx.x] = v;
    __syncthreads();
    for (int o = 1; o < 256; o <<= 1) {
        int u = (threadIdx.x >= o) ? sh[threadIdx.x - o] : 0;
        __syncthreads();
        sh[threadIdx.x] += u;
        __syncthreads();
    }
    if (i < N) incl[i] = sh[threadIdx.x];
    if (threadIdx.x == 255) bsum[blockIdx.x] = sh[255];
}

// single-block exclusive scan of block sums (nb <= 512)
__global__ void k_scan2(int* __restrict__ bsum, int nb) {
    __shared__ int sh[512];
    int t = threadIdx.x;
    int v = (t < nb) ? bsum[t] : 0;
    sh[t] = v;
    __syncthreads();
    for (int o = 1; o < 512; o <<= 1) {
        int u = (t >= o) ? sh[t - o] : 0;
        __syncthreads();
        sh[t] += u;
        __syncthreads();
    }
    if (t < nb) bsum[t] = sh[t] - v;  // exclusive
}

__global__ void k_scan3(const int* __restrict__ incl, const int* __restrict__ deg,
                        const int* __restrict__ bsum, int* __restrict__ offs, int N, int Etot) {
    int i = blockIdx.x * 256 + threadIdx.x;
    if (i < N) offs[i] = incl[i] - deg[i] + bsum[i >> 8];
    if (i == 0) offs[N] = Etot;
}

__global__ void k_scatter(const int* __restrict__ src, const int* __restrict__ dst, int E, int N,
                          const int* __restrict__ offs, int* __restrict__ cursor,
                          int* __restrict__ csr_src) {
    int i = blockIdx.x * 256 + threadIdx.x;
    if (i >= E + N) return;
    int d, s;
    if (i < E) { d = dst[i]; s = src[i]; }
    else       { d = i - E; s = i - E; }
    int pos = offs[d] + atomicAdd(&cursor[d], 1);
    csr_src[pos] = s;
}

// ---------------- GEMM: C[M x 128] = A[M x 128] @ W[128 x 128] ----------------
// 64x64 tile, 4x4 microtile, K-tiles of 32; A staged transposed in LDS.
// Dual-writes fp32 C and a bf16 copy Cb (gather-side copy for aggregation).

#define TM 64
#define TN 64
#define TK 32

__global__ __launch_bounds__(256) void k_gemm128(const float* __restrict__ A,
                                                 const float* __restrict__ W,
                                                 float* __restrict__ C,
                                                 ushort* __restrict__ Cb, int M) {
    __shared__ float As[TK][TM];  // As[k][m]
    __shared__ float Bs[TK][TN];  // Bs[k][n]
    int tid = threadIdx.x;
    int tx = tid & 15, ty = tid >> 4;
    int rowBase = blockIdx.y * TM;
    int col0 = blockIdx.x * TN;

    float acc[4][4] = {{0.f}};

    int arow = tid >> 2, akq = (tid & 3) * 8;   // A staging: 64 rows x 32 k, 8 floats/thread
    int brow = tid >> 3, bnq = (tid & 7) * 8;   // W staging: 32 k x 64 n, 8 floats/thread

    for (int k0 = 0; k0 < 128; k0 += TK) {
        int grow = rowBase + arow;
        float4 a0 = {0.f, 0.f, 0.f, 0.f}, a1 = {0.f, 0.f, 0.f, 0.f};
        if (grow < M) {
            const float* ap = A + (size_t)grow * 128 + k0 + akq;
            a0 = *(const float4*)ap;
            a1 = *(const float4*)(ap + 4);
        }
        const float* wp = W + (size_t)(k0 + brow) * 128 + col0 + bnq;
        float4 b0 = *(const float4*)wp;
        float4 b1 = *(const float4*)(wp + 4);

        __syncthreads();  // previous iteration's reads done before overwrite
        As[akq + 0][arow] = a0.x; As[akq + 1][arow] = a0.y;
        As[akq + 2][arow] = a0.z; As[akq + 3][arow] = a0.w;
        As[akq + 4][arow] = a1.x; As[akq + 5][arow] = a1.y;
        As[akq + 6][arow] = a1.z; As[akq + 7][arow] = a1.w;
        *(float4*)&Bs[brow][bnq]     = b0;
        *(float4*)&Bs[brow][bnq + 4] = b1;
        __syncthreads();

#pragma unroll
        for (int kk = 0; kk < TK; ++kk) {
            float4 av = *(const float4*)&As[kk][ty * 4];
            float4 bv = *(const float4*)&Bs[kk][tx * 4];
            acc[0][0] += av.x * bv.x; acc[0][1] += av.x * bv.y;
            acc[0][2] += av.x * bv.z; acc[0][3] += av.x * bv.w;
            acc[1][0] += av.y * bv.x; acc[1][1] += av.y * bv.y;
            acc[1][2] += av.y * bv.z; acc[1][3] += av.y * bv.w;
            acc[2][0] += av.z * bv.x; acc[2][1] += av.z * bv.y;
            acc[2][2] += av.z * bv.z; acc[2][3] += av.z * bv.w;
            acc[3][0] += av.w * bv.x; acc[3][1] += av.w * bv.y;
            acc[3][2] += av.w * bv.z; acc[3][3] += av.w * bv.w;
        }
    }

#pragma unroll
    for (int i = 0; i < 4; ++i) {
        int row = rowBase + ty * 4 + i;
        if (row < M) {
            float4 o = {acc[i][0], acc[i][1], acc[i][2], acc[i][3]};
            *(float4*)&C[(size_t)row * 128 + col0 + tx * 4] = o;
            ushort4 ob;
            ob.x = f2bf(o.x); ob.y = f2bf(o.y); ob.z = f2bf(o.z); ob.w = f2bf(o.w);
            *(ushort4*)&Cb[(size_t)row * 128 + col0 + tx * 4] = ob;
        }
    }
}

// ---------------- per-row attention dots: es = h . a_src, ed = h . a_dst ----------------

__global__ __launch_bounds__(256) void k_esed(const float* __restrict__ h,
                                              const float* __restrict__ a_s,
                                              const float* __restrict__ a_d,
                                              float* __restrict__ es, float* __restrict__ ed,
                                              int N) {
    int w = (blockIdx.x * blockDim.x + threadIdx.x) >> 6;
    int lane = threadIdx.x & 63;
    if (w >= N) return;
    float2 v   = ((const float2*)(h + (size_t)w * 128))[lane];
    float2 as2 = ((const float2*)a_s)[lane];
    float2 ad2 = ((const float2*)a_d)[lane];
    float s = v.x * as2.x + v.y * as2.y;
    float d = v.x * ad2.x + v.y * ad2.y;
#pragma unroll
    for (int o = 32; o; o >>= 1) {
        s += __shfl_xor(s, o);
        d += __shfl_xor(d, o);
    }
    if (lane == 0) { es[w] = s; ed[w] = d; }
}

// ---------------- per-node softmax + aggregation (wave per node) ----------------
// Gathers features from the bf16 copy (halves gather bytes); logits stay fp32.

__global__ __launch_bounds__(256) void k_aggregate(const ushort* __restrict__ hb,
                                                   const float* __restrict__ es,
                                                   const float* __restrict__ ed,
                                                   const int* __restrict__ csr_src,
                                                   const int* __restrict__ offs,
                                                   const float* __restrict__ bias,
                                                   float* __restrict__ out, int N) {
    int w = (blockIdx.x * blockDim.x + threadIdx.x) >> 6;
    int lane = threadIdx.x & 63;
    if (w >= N) return;
    int beg = offs[w], end = offs[w + 1];
    float edi = ed[w];

    // online softmax stats, lane-per-edge
    float m = -3.0e38f, s = 0.f;
    for (int j = beg + lane; j < end; j += WAVE) {
        int sj = csr_src[j];
        float e = es[sj] + edi;
        e = (e > 0.f) ? e : 0.2f * e;
        float mn = fmaxf(m, e);
        s = s * __expf(m - mn) + __expf(e - mn);
        m = mn;
    }
#pragma unroll
    for (int o = 32; o; o >>= 1) {
        float mo = __shfl_xor(m, o);
        float so = __shfl_xor(s, o);
        float mn = fmaxf(m, mo);
        s = s * __expf(m - mn) + so * __expf(mo - mn);
        m = mn;
    }
    float rinv = 1.f / s;

    float acc0 = 0.f, acc1 = 0.f;
    for (int j = beg; j < end; ++j) {
        int sj = csr_src[j];  // uniform across wave -> broadcast
        float e = es[sj] + edi;
        e = (e > 0.f) ? e : 0.2f * e;
        float wgt = __expf(e - m) * rinv;
        ushort2 raw = ((const ushort2*)(hb + (size_t)sj * 128))[lane];
        acc0 += wgt * bf2f(raw.x);
        acc1 += wgt * bf2f(raw.y);
    }
    float2 bv = ((const float2*)bias)[lane];
    float o0 = fmaxf(acc0 + bv.x, 0.f);
    float o1 = fmaxf(acc1 + bv.y, 0.f);
    ((float2*)(out + (size_t)w * 128))[lane] = make_float2(o0, o1);
}

// ---------------- pooling: parallel chunked sum with boundary-flush atomics ----------------

__global__ __launch_bounds__(128) void k_poolsum(const float* __restrict__ h,
                                                 const int* __restrict__ batch,
                                                 float* __restrict__ sums,   // [64][128]
                                                 int* __restrict__ cnt,      // [64]
                                                 int N) {
    int t = threadIdx.x;              // feature index
    int base = blockIdx.x * 256;      // 256-node chunk per block
    if (base >= N) return;
    int end = base + 256; if (end > N) end = N;

    int cur = batch[base];
    float acc = 0.f;
    int cnum = 0;
    for (int i = base; i < end; ++i) {
        int g = batch[i];
        if (g != cur) {
            atomicAdd(&sums[cur * 128 + t], acc);
            if (t == 0) atomicAdd(&cnt[cur], cnum);
            acc = 0.f; cnum = 0; cur = g;
        }
        acc += h[(size_t)i * 128 + t];
        ++cnum;
    }
    atomicAdd(&sums[cur * 128 + t], acc);
    if (t == 0) atomicAdd(&cnt[cur], cnum);
}

__global__ __launch_bounds__(64) void k_head(const float* __restrict__ sums,
                                             const int* __restrict__ cnt,
                                             const float* __restrict__ gf,
                                             const float* __restrict__ linW,
                                             const float* __restrict__ linb,
                                             float* __restrict__ out) {
    int g = blockIdx.x, t = threadIdx.x;
    __shared__ float feat[144];
    float c = fmaxf((float)cnt[g], 1.f);
    for (int k = t; k < 128; k += 64) feat[k] = sums[g * 128 + k] / c;
    if (t < 16) feat[128 + t] = gf[g * 16 + t];
    __syncthreads();
    if (t < 10) {
        float acc = linb[t];
        for (int k = 0; k < 144; ++k) acc += feat[k] * linW[k * 10 + t];
        out[g * 10 + t] = acc;
    }
}

// ---------------- launch ----------------

extern "C" void kernel_launch(void* const* d_in, const int* in_sizes, int n_in,
                              void* d_out, int out_size, void* d_ws, size_t ws_size,
                              hipStream_t stream) {
    const float* x    = (const float*)d_in[0];
    const int*   eidx = (const int*)d_in[1];
    const int*   batch = (const int*)d_in[2];
    const float* gf   = (const float*)d_in[3];
    const float* W1   = (const float*)d_in[4];
    const float* as1  = (const float*)d_in[5];
    const float* ad1  = (const float*)d_in[6];
    const float* b1   = (const float*)d_in[7];
    const float* W2   = (const float*)d_in[8];
    const float* as2  = (const float*)d_in[9];
    const float* ad2  = (const float*)d_in[10];
    const float* b2   = (const float*)d_in[11];
    const float* linW = (const float*)d_in[12];
    const float* linb = (const float*)d_in[13];
    float* out = (float*)d_out;

    const int N = in_sizes[0] / 128;
    const int E = in_sizes[1] / 2;
    const int Etot = E + N;
    const int* srcp = eidx;
    const int* dstp = eidx + E;

    char* ws = (char*)d_ws;
    size_t off = 0;
    auto alloc = [&](size_t bytes) -> void* {
        void* p = ws + off;
        off += (bytes + 255) & ~(size_t)255;
        return p;
    };
    float*  hA     = (float*)alloc((size_t)N * 128 * 4);   // GEMM fp32 out (both layers)
    ushort* hAb    = (ushort*)alloc((size_t)N * 128 * 2);  // GEMM bf16 out (gather copy)
    float*  hB     = (float*)alloc((size_t)N * 128 * 4);   // aggregate out (both layers)
    float*  es     = (float*)alloc((size_t)N * 4);
    float*  ed     = (float*)alloc((size_t)N * 4);
    int*    deg    = (int*)alloc((size_t)N * 4);
    int*    cursor = (int*)alloc((size_t)N * 4);
    int*    offs   = (int*)alloc((size_t)(N + 1) * 4);
    int*    incl   = (int*)alloc((size_t)N * 4);
    int*    bsum   = (int*)alloc(512 * 4);
    float*  psums  = (float*)alloc(64 * 128 * 4);
    int*    pcnt   = (int*)alloc(64 * 4);
    int*    csr    = (int*)alloc((size_t)Etot * 4);

    // ---- build CSR by dst (same for both layers) ----
    k_zero<<<(N + 255) / 256, 256, 0, stream>>>(deg, N);
    k_zero<<<(N + 255) / 256, 256, 0, stream>>>(cursor, N);
    // zero pooled sums (64*128 floats) + counts (64 ints): zero-bits == 0.0f
    k_zero<<<(64 * 128 + 64 + 255) / 256, 256, 0, stream>>>((int*)psums, 64 * 128 + 64);
    k_count<<<(Etot + 255) / 256, 256, 0, stream>>>(dstp, E, N, deg);
    int nb1 = (N + 255) / 256;
    k_scan1<<<nb1, 256, 0, stream>>>(deg, incl, bsum, N);
    k_scan2<<<1, 512, 0, stream>>>(bsum, nb1);
    k_scan3<<<nb1, 256, 0, stream>>>(incl, deg, bsum, offs, N, Etot);
    k_scatter<<<(Etot + 255) / 256, 256, 0, stream>>>(srcp, dstp, E, N, offs, cursor, csr);

    dim3 ggrid(128 / TN, (N + TM - 1) / TM);
    int wblocks = ((size_t)N * 64 + 255) / 256;

    // ---- layer 1 ----
    k_gemm128<<<ggrid, 256, 0, stream>>>(x, W1, hA, hAb, N);
    k_esed<<<wblocks, 256, 0, stream>>>(hA, as1, ad1, es, ed, N);
    k_aggregate<<<wblocks, 256, 0, stream>>>(hAb, es, ed, csr, offs, b1, hB, N);

    // ---- layer 2 ----
    k_gemm128<<<ggrid, 256, 0, stream>>>(hB, W2, hA, hAb, N);
    k_esed<<<wblocks, 256, 0, stream>>>(hA, as2, ad2, es, ed, N);
    k_aggregate<<<wblocks, 256, 0, stream>>>(hAb, es, ed, csr, offs, b2, hB, N);

    // ---- pool + head ----
    k_poolsum<<<(N + 255) / 256, 128, 0, stream>>>(hB, batch, psums, pcnt, N);
    k_head<<<64, 64, 0, stream>>>(psums, pcnt, gf, linW, linb, out);
}

// Round 4
// 569.337 us; speedup vs baseline: 1.8855x; 1.3227x over previous
//
#include <hip/hip_runtime.h>

#define WAVE 64

__device__ __forceinline__ ushort f2bf(float f) {
    union { float f; unsigned u; } v; v.f = f;
    unsigned r = v.u + 0x7FFF + ((v.u >> 16) & 1);
    return (ushort)(r >> 16);
}
__device__ __forceinline__ float bf2f(ushort u) {
    union { unsigned u; float f; } v; v.u = ((unsigned)u) << 16;
    return v.f;
}

// ---------------- utility kernels ----------------

__global__ void k_zero(int* __restrict__ p, int n) {
    int i = blockIdx.x * 256 + threadIdx.x;
    if (i < n) p[i] = 0;
}

__global__ void k_count(const int* __restrict__ dst, int E, int N, int* __restrict__ deg) {
    int i = blockIdx.x * 256 + threadIdx.x;
    if (i < E + N) {
        int d = (i < E) ? dst[i] : (i - E);
        atomicAdd(&deg[d], 1);
    }
}

// inclusive scan per 256-block
__global__ void k_scan1(const int* __restrict__ deg, int* __restrict__ incl,
                        int* __restrict__ bsum, int N) {
    __shared__ int sh[256];
    int i = blockIdx.x * 256 + threadIdx.x;
    int v = (i < N) ? deg[i] : 0;
    sh[threadIdx.x] = v;
    __syncthreads();
    for (int o = 1; o < 256; o <<= 1) {
        int u = (threadIdx.x >= o) ? sh[threadIdx.x - o] : 0;
        __syncthreads();
        sh[threadIdx.x] += u;
        __syncthreads();
    }
    if (i < N) incl[i] = sh[threadIdx.x];
    if (threadIdx.x == 255) bsum[blockIdx.x] = sh[255];
}

// single-block exclusive scan of block sums (nb <= 512)
__global__ void k_scan2(int* __restrict__ bsum, int nb) {
    __shared__ int sh[512];
    int t = threadIdx.x;
    int v = (t < nb) ? bsum[t] : 0;
    sh[t] = v;
    __syncthreads();
    for (int o = 1; o < 512; o <<= 1) {
        int u = (t >= o) ? sh[t - o] : 0;
        __syncthreads();
        sh[t] += u;
        __syncthreads();
    }
    if (t < nb) bsum[t] = sh[t] - v;  // exclusive
}

__global__ void k_scan3(const int* __restrict__ incl, const int* __restrict__ deg,
                        const int* __restrict__ bsum, int* __restrict__ offs, int N, int Etot) {
    int i = blockIdx.x * 256 + threadIdx.x;
    if (i < N) offs[i] = incl[i] - deg[i] + bsum[i >> 8];
    if (i == 0) offs[N] = Etot;
}

__global__ void k_scatter(const int* __restrict__ src, const int* __restrict__ dst, int E, int N,
                          const int* __restrict__ offs, int* __restrict__ cursor,
                          int* __restrict__ csr_src) {
    int i = blockIdx.x * 256 + threadIdx.x;
    if (i >= E + N) return;
    int d, s;
    if (i < E) { d = dst[i]; s = src[i]; }
    else       { d = i - E; s = i - E; }
    int pos = offs[d] + atomicAdd(&cursor[d], 1);
    csr_src[pos] = s;
}

// ---------------- GEMM: C[M x 128] = A[M x 128] @ W[128 x 128] ----------------
// 64x64 tile, 4x4 microtile, K-tiles of 32; A staged transposed in LDS.
// Dual-writes fp32 C and a bf16 copy Cb (gather-side copy for aggregation).

#define TM 64
#define TN 64
#define TK 32

__global__ __launch_bounds__(256) void k_gemm128(const float* __restrict__ A,
                                                 const float* __restrict__ W,
                                                 float* __restrict__ C,
                                                 ushort* __restrict__ Cb, int M) {
    __shared__ float As[TK][TM];  // As[k][m]
    __shared__ float Bs[TK][TN];  // Bs[k][n]
    int tid = threadIdx.x;
    int tx = tid & 15, ty = tid >> 4;
    int rowBase = blockIdx.y * TM;
    int col0 = blockIdx.x * TN;

    float acc[4][4] = {{0.f}};

    int arow = tid >> 2, akq = (tid & 3) * 8;   // A staging: 64 rows x 32 k, 8 floats/thread
    int brow = tid >> 3, bnq = (tid & 7) * 8;   // W staging: 32 k x 64 n, 8 floats/thread

    for (int k0 = 0; k0 < 128; k0 += TK) {
        int grow = rowBase + arow;
        float4 a0 = {0.f, 0.f, 0.f, 0.f}, a1 = {0.f, 0.f, 0.f, 0.f};
        if (grow < M) {
            const float* ap = A + (size_t)grow * 128 + k0 + akq;
            a0 = *(const float4*)ap;
            a1 = *(const float4*)(ap + 4);
        }
        const float* wp = W + (size_t)(k0 + brow) * 128 + col0 + bnq;
        float4 b0 = *(const float4*)wp;
        float4 b1 = *(const float4*)(wp + 4);

        __syncthreads();  // previous iteration's reads done before overwrite
        As[akq + 0][arow] = a0.x; As[akq + 1][arow] = a0.y;
        As[akq + 2][arow] = a0.z; As[akq + 3][arow] = a0.w;
        As[akq + 4][arow] = a1.x; As[akq + 5][arow] = a1.y;
        As[akq + 6][arow] = a1.z; As[akq + 7][arow] = a1.w;
        *(float4*)&Bs[brow][bnq]     = b0;
        *(float4*)&Bs[brow][bnq + 4] = b1;
        __syncthreads();

#pragma unroll
        for (int kk = 0; kk < TK; ++kk) {
            float4 av = *(const float4*)&As[kk][ty * 4];
            float4 bv = *(const float4*)&Bs[kk][tx * 4];
            acc[0][0] += av.x * bv.x; acc[0][1] += av.x * bv.y;
            acc[0][2] += av.x * bv.z; acc[0][3] += av.x * bv.w;
            acc[1][0] += av.y * bv.x; acc[1][1] += av.y * bv.y;
            acc[1][2] += av.y * bv.z; acc[1][3] += av.y * bv.w;
            acc[2][0] += av.z * bv.x; acc[2][1] += av.z * bv.y;
            acc[2][2] += av.z * bv.z; acc[2][3] += av.z * bv.w;
            acc[3][0] += av.w * bv.x; acc[3][1] += av.w * bv.y;
            acc[3][2] += av.w * bv.z; acc[3][3] += av.w * bv.w;
        }
    }

#pragma unroll
    for (int i = 0; i < 4; ++i) {
        int row = rowBase + ty * 4 + i;
        if (row < M) {
            float4 o = {acc[i][0], acc[i][1], acc[i][2], acc[i][3]};
            *(float4*)&C[(size_t)row * 128 + col0 + tx * 4] = o;
            ushort4 ob;
            ob.x = f2bf(o.x); ob.y = f2bf(o.y); ob.z = f2bf(o.z); ob.w = f2bf(o.w);
            *(ushort4*)&Cb[(size_t)row * 128 + col0 + tx * 4] = ob;
        }
    }
}

// ---------------- per-row attention dots: es = h . a_src, ed = h . a_dst ----------------

__global__ __launch_bounds__(256) void k_esed(const float* __restrict__ h,
                                              const float* __restrict__ a_s,
                                              const float* __restrict__ a_d,
                                              float* __restrict__ es, float* __restrict__ ed,
                                              int N) {
    int w = (blockIdx.x * blockDim.x + threadIdx.x) >> 6;
    int lane = threadIdx.x & 63;
    if (w >= N) return;
    float2 v   = ((const float2*)(h + (size_t)w * 128))[lane];
    float2 as2 = ((const float2*)a_s)[lane];
    float2 ad2 = ((const float2*)a_d)[lane];
    float s = v.x * as2.x + v.y * as2.y;
    float d = v.x * ad2.x + v.y * ad2.y;
#pragma unroll
    for (int o = 32; o; o >>= 1) {
        s += __shfl_xor(s, o);
        d += __shfl_xor(d, o);
    }
    if (lane == 0) { es[w] = s; ed[w] = d; }
}

// ---------------- per-node softmax + aggregation (wave per node) ----------------
// Flash-style 64-edge tiles: lane-parallel stats, (p,src) staged in per-wave LDS,
// then a 2-way-unrolled gather-accumulate with dual accumulators. Normalize once at end.

__global__ __launch_bounds__(256) void k_aggregate(const ushort* __restrict__ hb,
                                                   const float* __restrict__ es,
                                                   const float* __restrict__ ed,
                                                   const int* __restrict__ csr_src,
                                                   const int* __restrict__ offs,
                                                   const float* __restrict__ bias,
                                                   float* __restrict__ out, int N) {
    __shared__ __align__(16) float2 pe[4][64];   // per-wave (p, src) staging
    int wid  = threadIdx.x >> 6;
    int lane = threadIdx.x & 63;
    int w = (blockIdx.x * 256 + threadIdx.x) >> 6;
    if (w >= N) return;
    int beg = offs[w], end = offs[w + 1];
    float edi = ed[w];

    float m = -3.0e38f, s = 0.f;
    float a0x = 0.f, a0y = 0.f, a1x = 0.f, a1y = 0.f;

    for (int tb = beg; tb < end; tb += WAVE) {
        int cnt = end - tb; if (cnt > WAVE) cnt = WAVE;

        // ---- lane-parallel stats for this tile ----
        float e = -3.0e38f;
        int sj = 0;
        if (lane < cnt) {
            sj = csr_src[tb + lane];
            float t = es[sj] + edi;
            e = (t > 0.f) ? t : 0.2f * t;
        }
        float tm = e;
#pragma unroll
        for (int o = 32; o; o >>= 1) tm = fmaxf(tm, __shfl_xor(tm, o));
        float mn = fmaxf(m, tm);
        float p = __expf(e - mn);            // 0 for inactive lanes
        float ts = p;
#pragma unroll
        for (int o = 32; o; o >>= 1) ts += __shfl_xor(ts, o);
        float scale = __expf(m - mn);        // rescale previous tiles (0 on first)
        s = s * scale + ts;
        a0x *= scale; a0y *= scale; a1x *= scale; a1y *= scale;
        m = mn;

        pe[wid][lane] = make_float2(p, __int_as_float(sj));
        asm volatile("s_waitcnt lgkmcnt(0)" ::: "memory");  // wave-local LDS RAW fence

        // ---- gather-accumulate, 2 edges/iter, dual accumulators ----
        int k = 0;
        for (; k + 2 <= cnt; k += 2) {
            float4 t2 = *(const float4*)&pe[wid][k];
            int s0 = __float_as_int(t2.y);
            int s1 = __float_as_int(t2.w);
            ushort2 r0 = ((const ushort2*)(hb + (size_t)s0 * 128))[lane];
            ushort2 r1 = ((const ushort2*)(hb + (size_t)s1 * 128))[lane];
            a0x += t2.x * bf2f(r0.x); a0y += t2.x * bf2f(r0.y);
            a1x += t2.z * bf2f(r1.x); a1y += t2.z * bf2f(r1.y);
        }
        if (k < cnt) {
            float2 t1 = pe[wid][k];
            int s0 = __float_as_int(t1.y);
            ushort2 r0 = ((const ushort2*)(hb + (size_t)s0 * 128))[lane];
            a0x += t1.x * bf2f(r0.x); a0y += t1.x * bf2f(r0.y);
        }
    }

    float rinv = 1.f / s;
    float2 bv = ((const float2*)bias)[lane];
    float o0 = fmaxf((a0x + a1x) * rinv + bv.x, 0.f);
    float o1 = fmaxf((a0y + a1y) * rinv + bv.y, 0.f);
    ((float2*)(out + (size_t)w * 128))[lane] = make_float2(o0, o1);
}

// ---------------- pooling: parallel chunked sum with boundary-flush atomics ----------------

__global__ __launch_bounds__(128) void k_poolsum(const float* __restrict__ h,
                                                 const int* __restrict__ batch,
                                                 float* __restrict__ sums,   // [64][128]
                                                 int* __restrict__ cnt,      // [64]
                                                 int N) {
    int t = threadIdx.x;              // feature index
    int base = blockIdx.x * 256;      // 256-node chunk per block
    if (base >= N) return;
    int end = base + 256; if (end > N) end = N;

    int cur = batch[base];
    float acc = 0.f;
    int cnum = 0;
    for (int i = base; i < end; ++i) {
        int g = batch[i];
        if (g != cur) {
            atomicAdd(&sums[cur * 128 + t], acc);
            if (t == 0) atomicAdd(&cnt[cur], cnum);
            acc = 0.f; cnum = 0; cur = g;
        }
        acc += h[(size_t)i * 128 + t];
        ++cnum;
    }
    atomicAdd(&sums[cur * 128 + t], acc);
    if (t == 0) atomicAdd(&cnt[cur], cnum);
}

__global__ __launch_bounds__(64) void k_head(const float* __restrict__ sums,
                                             const int* __restrict__ cnt,
                                             const float* __restrict__ gf,
                                             const float* __restrict__ linW,
                                             const float* __restrict__ linb,
                                             float* __restrict__ out) {
    int g = blockIdx.x, t = threadIdx.x;
    __shared__ float feat[144];
    float c = fmaxf((float)cnt[g], 1.f);
    for (int k = t; k < 128; k += 64) feat[k] = sums[g * 128 + k] / c;
    if (t < 16) feat[128 + t] = gf[g * 16 + t];
    __syncthreads();
    if (t < 10) {
        float acc = linb[t];
        for (int k = 0; k < 144; ++k) acc += feat[k] * linW[k * 10 + t];
        out[g * 10 + t] = acc;
    }
}

// ---------------- launch ----------------

extern "C" void kernel_launch(void* const* d_in, const int* in_sizes, int n_in,
                              void* d_out, int out_size, void* d_ws, size_t ws_size,
                              hipStream_t stream) {
    const float* x    = (const float*)d_in[0];
    const int*   eidx = (const int*)d_in[1];
    const int*   batch = (const int*)d_in[2];
    const float* gf   = (const float*)d_in[3];
    const float* W1   = (const float*)d_in[4];
    const float* as1  = (const float*)d_in[5];
    const float* ad1  = (const float*)d_in[6];
    const float* b1   = (const float*)d_in[7];
    const float* W2   = (const float*)d_in[8];
    const float* as2  = (const float*)d_in[9];
    const float* ad2  = (const float*)d_in[10];
    const float* b2   = (const float*)d_in[11];
    const float* linW = (const float*)d_in[12];
    const float* linb = (const float*)d_in[13];
    float* out = (float*)d_out;

    const int N = in_sizes[0] / 128;
    const int E = in_sizes[1] / 2;
    const int Etot = E + N;
    const int* srcp = eidx;
    const int* dstp = eidx + E;

    char* ws = (char*)d_ws;
    size_t off = 0;
    auto alloc = [&](size_t bytes) -> void* {
        void* p = ws + off;
        off += (bytes + 255) & ~(size_t)255;
        return p;
    };
    float*  hA     = (float*)alloc((size_t)N * 128 * 4);   // GEMM fp32 out (both layers)
    ushort* hAb    = (ushort*)alloc((size_t)N * 128 * 2);  // GEMM bf16 out (gather copy)
    float*  hB     = (float*)alloc((size_t)N * 128 * 4);   // aggregate out (both layers)
    float*  es     = (float*)alloc((size_t)N * 4);
    float*  ed     = (float*)alloc((size_t)N * 4);
    int*    deg    = (int*)alloc((size_t)N * 4);
    int*    cursor = (int*)alloc((size_t)N * 4);
    int*    offs   = (int*)alloc((size_t)(N + 1) * 4);
    int*    incl   = (int*)alloc((size_t)N * 4);
    int*    bsum   = (int*)alloc(512 * 4);
    float*  psums  = (float*)alloc(64 * 128 * 4);
    int*    pcnt   = (int*)alloc(64 * 4);
    int*    csr    = (int*)alloc((size_t)Etot * 4);

    // ---- build CSR by dst (same for both layers) ----
    k_zero<<<(N + 255) / 256, 256, 0, stream>>>(deg, N);
    k_zero<<<(N + 255) / 256, 256, 0, stream>>>(cursor, N);
    // zero pooled sums (64*128 floats) + counts (64 ints): zero-bits == 0.0f
    k_zero<<<(64 * 128 + 64 + 255) / 256, 256, 0, stream>>>((int*)psums, 64 * 128 + 64);
    k_count<<<(Etot + 255) / 256, 256, 0, stream>>>(dstp, E, N, deg);
    int nb1 = (N + 255) / 256;
    k_scan1<<<nb1, 256, 0, stream>>>(deg, incl, bsum, N);
    k_scan2<<<1, 512, 0, stream>>>(bsum, nb1);
    k_scan3<<<nb1, 256, 0, stream>>>(incl, deg, bsum, offs, N, Etot);
    k_scatter<<<(Etot + 255) / 256, 256, 0, stream>>>(srcp, dstp, E, N, offs, cursor, csr);

    dim3 ggrid(128 / TN, (N + TM - 1) / TM);
    int wblocks = ((size_t)N * 64 + 255) / 256;

    // ---- layer 1 ----
    k_gemm128<<<ggrid, 256, 0, stream>>>(x, W1, hA, hAb, N);
    k_esed<<<wblocks, 256, 0, stream>>>(hA, as1, ad1, es, ed, N);
    k_aggregate<<<wblocks, 256, 0, stream>>>(hAb, es, ed, csr, offs, b1, hB, N);

    // ---- layer 2 ----
    k_gemm128<<<ggrid, 256, 0, stream>>>(hB, W2, hA, hAb, N);
    k_esed<<<wblocks, 256, 0, stream>>>(hA, as2, ad2, es, ed, N);
    k_aggregate<<<wblocks, 256, 0, stream>>>(hAb, es, ed, csr, offs, b2, hB, N);

    // ---- pool + head ----
    k_poolsum<<<(N + 255) / 256, 128, 0, stream>>>(hB, batch, psums, pcnt, N);
    k_head<<<64, 64, 0, stream>>>(psums, pcnt, gf, linW, linb, out);
}